// Round 8
// baseline (1577.364 us; speedup 1.0000x reference)
//
#include <hip/hip_runtime.h>
#include <math.h>

#define D 128
#define NB 16           // Cholesky panel width
#define RPB 64          // rows per block in the GEMM kernel
#define NBUK_MAX 1024   // max buckets (n <= 131072)
#define RPBUK 128       // rows per bucket
#define EPB 16384       // edges per partition block
#define ALPHA 0.1f
#define LAMDA 0.5f

// ---------------- K1: A = W^T W + 1e-4 I  (tiny) ----------------
__global__ __launch_bounds__(256) void wtw_kernel(const float* __restrict__ W,
                                                  float* __restrict__ A) {
    int idx = blockIdx.x * blockDim.x + threadIdx.x;
    int i = idx >> 7, j = idx & (D - 1);
    float acc = (i == j) ? 1e-4f : 0.0f;
#pragma unroll 4
    for (int k = 0; k < D; ++k) acc = fmaf(W[k * D + i], W[k * D + j], acc);
    A[idx] = acc;
}

// ---------------- K2a: one-block BLOCKED Cholesky (NB=16) ----------------
__global__ __launch_bounds__(256) void chol_factor_kernel(const float* __restrict__ A_in,
                                                          float* __restrict__ Lg) {
    __shared__ float S[D][D];
    __shared__ float dinvS[NB];
    const int tid = threadIdx.x;
    const int tx = tid & 15;
    const int ty = tid >> 4;

    for (int i = tid; i < D * D; i += 256) ((float*)S)[i] = A_in[i];
    __syncthreads();

    for (int s = 0; s < D / NB; ++s) {
        const int b = s * NB;

        for (int k = 0; k < NB; ++k) {
            float dk  = S[b + k][b + k];
            float a_i = S[b + k][b + tx];
            float a_j = S[b + k][b + ty];
            float lkk  = sqrtf(dk);
            float inv  = 1.0f / lkk;
            float invd = inv * inv;
            __syncthreads();
            if (ty == 0) {
                if (tx == k)       { S[b + k][b + k] = lkk; dinvS[k] = inv; }
                else if (tx > k)     S[b + k][b + tx] = a_i * inv;
            }
            if (ty > k && tx >= ty)
                S[b + ty][b + tx] -= a_i * (a_j * invd);
            __syncthreads();
        }

        const int m = D - b - NB;

        if (m > 0 && tid < m) {
            const int r = b + NB + tid;
            float y[NB];
#pragma unroll
            for (int k = 0; k < NB; ++k) y[k] = S[b + k][r];
#pragma unroll
            for (int k = 0; k < NB; ++k) {
                float acc = y[k];
#pragma unroll
                for (int q = 0; q < NB; ++q)
                    if (q < k) acc -= S[b + q][b + k] * y[q];
                y[k] = acc * dinvS[k];
            }
#pragma unroll
            for (int k = 0; k < NB; ++k) S[b + k][r] = y[k];
        }
        __syncthreads();

        const int nt = m >> 4;
        for (int tc = 0; tc < nt; ++tc) {
            for (int tr = tc; tr < nt; ++tr) {
                const int c = b + NB + tc * 16 + ty;
                const int r = b + NB + tr * 16 + tx;
                if (r >= c) {
                    float acc = S[c][r];
#pragma unroll
                    for (int k = 0; k < NB; ++k)
                        acc -= S[b + k][r] * S[b + k][c];
                    S[c][r] = acc;
                }
            }
        }
        __syncthreads();
    }

    for (int i = tid; i < D * D; i += 256) Lg[i] = ((float*)S)[i];
}

// ---------------- K2b: parallel triangular solve + build M ---------------
__global__ __launch_bounds__(64) void solve_m_kernel(const float* __restrict__ Lg,
                                                     const float* __restrict__ W,
                                                     const int* __restrict__ lp,
                                                     float* __restrict__ Mg) {
    __shared__ float Lr[D][D + 1];
    const int lane = threadIdx.x;
    const int c = blockIdx.x;

    for (int j = 0; j < D; ++j) {
        Lr[lane][j]      = Lg[j * D + lane];
        Lr[lane + 64][j] = Lg[j * D + lane + 64];
    }
    __syncthreads();

    const float w_lo = W[c * D + lane];
    const float w_hi = W[c * D + 64 + lane];
    const float dinv_lo = 1.0f / Lr[lane][lane];
    const float dinv_hi = 1.0f / Lr[lane + 64][lane + 64];
    float y_lo = 0.0f, y_hi = 0.0f;

    for (int i = 0; i < D; ++i) {
        float l0 = Lr[i][lane];
        float l1 = Lr[i][lane + 64];
        float p = 0.0f;
        p += (lane < i)      ? l0 * y_lo : 0.0f;
        p += (lane + 64 < i) ? l1 * y_hi : 0.0f;
#pragma unroll
        for (int off = 32; off >= 1; off >>= 1) p += __shfl_xor(p, off);
        if (i < 64) {
            if (lane == i)      y_lo = (w_lo - p) * dinv_lo;
        } else {
            if (lane == i - 64) y_hi = (w_hi - p) * dinv_hi;
        }
    }

    const float th = logf(LAMDA / (float)(*lp) + 1.0f);
    float m_lo = th * y_lo + ((c == lane)      ? (1.0f - th) : 0.0f);
    float m_hi = th * y_hi + ((c == lane + 64) ? (1.0f - th) : 0.0f);
    Mg[c * D + lane]      = m_lo;
    Mg[c * D + 64 + lane] = m_hi;
}

// ---------------- x -> bf16 conversion (RNE) -----------------------------
__global__ __launch_bounds__(256) void cvt_bf16_kernel(const float* __restrict__ x,
                                                       unsigned short* __restrict__ xb,
                                                       int nd) {
    const int base = (blockIdx.x * 256 + threadIdx.x) * 8;
    if (base + 7 < nd) {
        float4 a = *reinterpret_cast<const float4*>(x + base);
        float4 b = *reinterpret_cast<const float4*>(x + base + 4);
        unsigned r[8];
        const float* f = &a.x;
#pragma unroll
        for (int i = 0; i < 4; ++i) {
            unsigned u = __float_as_uint(f[i]);
            r[i] = (u + 0x7FFFu + ((u >> 16) & 1u)) >> 16;
        }
        const float* g = &b.x;
#pragma unroll
        for (int i = 0; i < 4; ++i) {
            unsigned u = __float_as_uint(g[i]);
            r[4 + i] = (u + 0x7FFFu + ((u >> 16) & 1u)) >> 16;
        }
        uint4 o;
        o.x = r[0] | (r[1] << 16);
        o.y = r[2] | (r[3] << 16);
        o.z = r[4] | (r[5] << 16);
        o.w = r[6] | (r[7] << 16);
        *reinterpret_cast<uint4*>(xb + base) = o;
    } else {
        for (int i = 0; i < 8 && base + i < nd; ++i) {
            unsigned u = __float_as_uint(x[base + i]);
            xb[base + i] = (unsigned short)((u + 0x7FFFu + ((u >> 16) & 1u)) >> 16);
        }
    }
}

// ---------------- Bucket partition: count -> scan -> partition -----------
// Bucket b = row >> 7 (128 rows/bucket). Edges land bucket-contiguous with
// frontier-local writes (no fully-random 8B scatter).
__global__ __launch_bounds__(256) void count_bucket_kernel(const int* __restrict__ rows,
                                                           int* __restrict__ bcnt,
                                                           int E, int nbuk) {
    __shared__ int lcnt[NBUK_MAX];
    const int tid = threadIdx.x;
    const int e0 = blockIdx.x * EPB;
    const int e1 = min(e0 + EPB, E);
    for (int i = tid; i < nbuk; i += 256) lcnt[i] = 0;
    __syncthreads();
    for (int e = e0 + tid * 4; e < e1; e += 1024) {
        if (e + 3 < e1) {
            int4 r = *reinterpret_cast<const int4*>(rows + e);
            atomicAdd(&lcnt[r.x >> 7], 1);
            atomicAdd(&lcnt[r.y >> 7], 1);
            atomicAdd(&lcnt[r.z >> 7], 1);
            atomicAdd(&lcnt[r.w >> 7], 1);
        } else {
            int lim = min(e + 4, e1);
            for (int k = e; k < lim; ++k) atomicAdd(&lcnt[rows[k] >> 7], 1);
        }
    }
    __syncthreads();
    for (int i = tid; i < nbuk; i += 256) {
        int c = lcnt[i];
        if (c) atomicAdd(&bcnt[i], c);
    }
}

// Exclusive scan of bucket counts (nbuk <= 1024, one block).
__global__ __launch_bounds__(1024) void scan_bucket_kernel(const int* __restrict__ bcnt,
                                                           int* __restrict__ bbase,
                                                           int* __restrict__ gcur,
                                                           int nbuk) {
    __shared__ int ps[1024];
    const int tid = threadIdx.x;
    int v = (tid < nbuk) ? bcnt[tid] : 0;
    ps[tid] = v;
    __syncthreads();
    for (int off = 1; off < 1024; off <<= 1) {
        int t = (tid >= off) ? ps[tid - off] : 0;
        __syncthreads();
        ps[tid] += t;
        __syncthreads();
    }
    if (tid < nbuk) {
        int excl = ps[tid] - v;
        bbase[tid] = excl;
        gcur[tid]  = excl;
    }
}

// Partition edges into buckets: meta = col | (row&127)<<20, plus f32 val.
// After this kernel gcur[b] == end of bucket b (start == bbase[b]).
__global__ __launch_bounds__(256) void partition_kernel(const int* __restrict__ rows,
                                                        const int* __restrict__ cols,
                                                        const float* __restrict__ vals,
                                                        int* __restrict__ gcur,
                                                        uint2* __restrict__ buk,
                                                        int E, int nbuk) {
    __shared__ int lcnt[NBUK_MAX];
    __shared__ int lbase[NBUK_MAX];
    __shared__ int loff[NBUK_MAX];
    const int tid = threadIdx.x;
    const int e0 = blockIdx.x * EPB;
    const int e1 = min(e0 + EPB, E);
    for (int i = tid; i < nbuk; i += 256) { lcnt[i] = 0; loff[i] = 0; }
    __syncthreads();
    for (int e = e0 + tid * 4; e < e1; e += 1024) {
        if (e + 3 < e1) {
            int4 r = *reinterpret_cast<const int4*>(rows + e);
            atomicAdd(&lcnt[r.x >> 7], 1);
            atomicAdd(&lcnt[r.y >> 7], 1);
            atomicAdd(&lcnt[r.z >> 7], 1);
            atomicAdd(&lcnt[r.w >> 7], 1);
        } else {
            int lim = min(e + 4, e1);
            for (int k = e; k < lim; ++k) atomicAdd(&lcnt[rows[k] >> 7], 1);
        }
    }
    __syncthreads();
    for (int i = tid; i < nbuk; i += 256) {
        int c = lcnt[i];
        if (c) lbase[i] = atomicAdd(&gcur[i], c);
    }
    __syncthreads();
    for (int e = e0 + tid * 4; e < e1; e += 1024) {
        if (e + 3 < e1) {
            int4 r = *reinterpret_cast<const int4*>(rows + e);
            int4 c = *reinterpret_cast<const int4*>(cols + e);
            float4 v = *reinterpret_cast<const float4*>(vals + e);
            {
                int b = r.x >> 7; int li = atomicAdd(&loff[b], 1);
                buk[lbase[b] + li] = make_uint2((unsigned)c.x | ((unsigned)(r.x & 127) << 20), __float_as_uint(v.x));
            }
            {
                int b = r.y >> 7; int li = atomicAdd(&loff[b], 1);
                buk[lbase[b] + li] = make_uint2((unsigned)c.y | ((unsigned)(r.y & 127) << 20), __float_as_uint(v.y));
            }
            {
                int b = r.z >> 7; int li = atomicAdd(&loff[b], 1);
                buk[lbase[b] + li] = make_uint2((unsigned)c.z | ((unsigned)(r.z & 127) << 20), __float_as_uint(v.z));
            }
            {
                int b = r.w >> 7; int li = atomicAdd(&loff[b], 1);
                buk[lbase[b] + li] = make_uint2((unsigned)c.w | ((unsigned)(r.w & 127) << 20), __float_as_uint(v.w));
            }
        } else {
            int lim = min(e + 4, e1);
            for (int k = e; k < lim; ++k) {
                int rr = rows[k];
                int b = rr >> 7; int li = atomicAdd(&loff[b], 1);
                buk[lbase[b] + li] = make_uint2((unsigned)cols[k] | ((unsigned)(rr & 127) << 20), __float_as_uint(vals[k]));
            }
        }
    }
}

// ---------------- K3: bucketed SpMM with LDS f32 accumulator -------------
// Block b owns rows [b*128, b*128+128). Each wave streams edges (8-deep),
// gathers 4B/lane of the bf16 x-row, ds_add_f32 into the LDS tile.
__global__ __launch_bounds__(256) void spmm_bucket_kernel(
        const unsigned short* __restrict__ xb,
        const float* __restrict__ h0,
        const uint2* __restrict__ buk,
        const int* __restrict__ bbase,
        const int* __restrict__ bend,
        float* __restrict__ S, int n) {
    __shared__ float acc[RPBUK][D];    // 64 KiB
    const int tid = threadIdx.x;
    const int b = blockIdx.x;

    float4* av = (float4*)&acc[0][0];
    const float4 z = make_float4(0.f, 0.f, 0.f, 0.f);
    for (int i = tid; i < RPBUK * D / 4; i += 256) av[i] = z;
    __syncthreads();

    const int start = bbase[b], end = bend[b];
    const int wid = tid >> 6, lane = tid & 63;
    const int c0 = lane * 2;

    for (int j0 = start + wid; j0 < end; j0 += 4 * 8) {
        uint2 e[8];
        unsigned xw[8];
#pragma unroll
        for (int u = 0; u < 8; ++u) {
            int j = j0 + 4 * u;
            e[u] = (j < end) ? buk[j] : make_uint2(0xFFFFFFFFu, 0u);
        }
#pragma unroll
        for (int u = 0; u < 8; ++u) {
            if (e[u].x != 0xFFFFFFFFu) {
                unsigned col = e[u].x & 0xFFFFFu;
                xw[u] = *reinterpret_cast<const unsigned*>(xb + (size_t)col * D + c0);
            }
        }
#pragma unroll
        for (int u = 0; u < 8; ++u) {
            if (e[u].x == 0xFFFFFFFFu) continue;
            int rl = e[u].x >> 20;
            float v = __uint_as_float(e[u].y);
            float lo = __uint_as_float(xw[u] << 16);
            float hi = __uint_as_float(xw[u] & 0xffff0000u);
            unsafeAtomicAdd(&acc[rl][c0],     v * lo);
            unsafeAtomicAdd(&acc[rl][c0 + 1], v * hi);
        }
    }
    __syncthreads();

    // Epilogue: S = 0.9*acc + 0.1*h0
    for (int idx = tid; idx < RPBUK * D / 4; idx += 256) {
        int row = idx >> 5;
        int c4 = (idx & 31) * 4;
        int r = b * RPBUK + row;
        if (r >= n) continue;
        float4 a = *reinterpret_cast<float4*>(&acc[row][c4]);
        float4 h = *reinterpret_cast<const float4*>(h0 + (size_t)r * D + c4);
        float4 s;
        s.x = 0.9f * a.x + 0.1f * h.x;
        s.y = 0.9f * a.y + 0.1f * h.y;
        s.z = 0.9f * a.z + 0.1f * h.z;
        s.w = 0.9f * a.w + 0.1f * h.w;
        *reinterpret_cast<float4*>(S + (size_t)r * D + c4) = s;
    }
}

// -------- Fallback (atomic scatter) if workspace is too small -------------
__global__ __launch_bounds__(256) void spmm_atomic_kernel(const float* __restrict__ x,
                                                          const float* __restrict__ vals,
                                                          const int* __restrict__ rows,
                                                          const int* __restrict__ cols,
                                                          float* __restrict__ hi, int E) {
    int tid = blockIdx.x * blockDim.x + threadIdx.x;
    int e = tid >> 5;
    if (e >= E) return;
    int q = tid & 31;
    float v = vals[e];
    int c = cols[e];
    int r = rows[e];
    const float4 xv = *reinterpret_cast<const float4*>(x + (size_t)c * D + q * 4);
    float* h = hi + (size_t)r * D + q * 4;
    unsafeAtomicAdd(h + 0, v * xv.x);
    unsafeAtomicAdd(h + 1, v * xv.y);
    unsafeAtomicAdd(h + 2, v * xv.z);
    unsafeAtomicAdd(h + 3, v * xv.w);
}

__global__ __launch_bounds__(256) void blend_kernel(const float* __restrict__ hi,
                                                    const float* __restrict__ h0,
                                                    float* __restrict__ S, int nd4) {
    int i = blockIdx.x * blockDim.x + threadIdx.x;
    if (i >= nd4) return;
    float4 a = reinterpret_cast<const float4*>(hi)[i];
    float4 b = reinterpret_cast<const float4*>(h0)[i];
    float4 s;
    s.x = 0.9f * a.x + 0.1f * b.x;
    s.y = 0.9f * a.y + 0.1f * b.y;
    s.z = 0.9f * a.z + 0.1f * b.z;
    s.w = 0.9f * a.w + 0.1f * b.w;
    reinterpret_cast<float4*>(S)[i] = s;
}

// ---------------- K4: out = tanh(S @ M), 64 rows/block, 4x8/thread -------
__global__ __launch_bounds__(256) void gemm_tanh_kernel(const float* __restrict__ S,
                                                        const float* __restrict__ Mg,
                                                        float* __restrict__ out, int n) {
    __shared__ float Ms[64][D];
    __shared__ float Ss[RPB][D + 1];
    const int tid = threadIdx.x;
    const int r0  = blockIdx.x * RPB;

    for (int i = tid; i < RPB * D / 4; i += 256) {
        int rr = (i * 4) / D, cc = (i * 4) & (D - 1);
        int r = r0 + rr;
        float4 a = (r < n) ? *reinterpret_cast<const float4*>(S + (size_t)r * D + cc)
                           : make_float4(0.f, 0.f, 0.f, 0.f);
        Ss[rr][cc + 0] = a.x;
        Ss[rr][cc + 1] = a.y;
        Ss[rr][cc + 2] = a.z;
        Ss[rr][cc + 3] = a.w;
    }

    const int tc = tid & 15;
    const int tr = tid >> 4;
    float acc[4][8] = {};

    for (int kb = 0; kb < 2; ++kb) {
        __syncthreads();
        for (int i = tid; i < 64 * D / 4; i += 256)
            reinterpret_cast<float4*>(&Ms[0][0])[i] =
                reinterpret_cast<const float4*>(Mg + kb * 64 * D)[i];
        __syncthreads();
#pragma unroll 4
        for (int kk = 0; kk < 64; ++kk) {
            int k = kb * 64 + kk;
            float4 b0 = *reinterpret_cast<const float4*>(&Ms[kk][tc * 4]);
            float4 b1 = *reinterpret_cast<const float4*>(&Ms[kk][64 + tc * 4]);
#pragma unroll
            for (int m = 0; m < 4; ++m) {
                float a = Ss[4 * tr + m][k];
                acc[m][0] = fmaf(a, b0.x, acc[m][0]);
                acc[m][1] = fmaf(a, b0.y, acc[m][1]);
                acc[m][2] = fmaf(a, b0.z, acc[m][2]);
                acc[m][3] = fmaf(a, b0.w, acc[m][3]);
                acc[m][4] = fmaf(a, b1.x, acc[m][4]);
                acc[m][5] = fmaf(a, b1.y, acc[m][5]);
                acc[m][6] = fmaf(a, b1.z, acc[m][6]);
                acc[m][7] = fmaf(a, b1.w, acc[m][7]);
            }
        }
    }

#pragma unroll
    for (int m = 0; m < 4; ++m) {
        int r = r0 + 4 * tr + m;
        if (r >= n) continue;
        float4 o0, o1;
        o0.x = tanhf(acc[m][0]); o0.y = tanhf(acc[m][1]);
        o0.z = tanhf(acc[m][2]); o0.w = tanhf(acc[m][3]);
        o1.x = tanhf(acc[m][4]); o1.y = tanhf(acc[m][5]);
        o1.z = tanhf(acc[m][6]); o1.w = tanhf(acc[m][7]);
        *reinterpret_cast<float4*>(out + (size_t)r * D + tc * 4)      = o0;
        *reinterpret_cast<float4*>(out + (size_t)r * D + 64 + tc * 4) = o1;
    }
}

extern "C" void kernel_launch(void* const* d_in, const int* in_sizes, int n_in,
                              void* d_out, int out_size, void* d_ws, size_t ws_size,
                              hipStream_t stream) {
    const float* x  = (const float*)d_in[0];
    const float* h0 = (const float*)d_in[1];
    const float* W  = (const float*)d_in[2];
    const float* av = (const float*)d_in[3];
    const int*   ar = (const int*)d_in[4];
    const int*   ac = (const int*)d_in[5];
    const int*   lp = (const int*)d_in[6];
    float* out = (float*)d_out;

    const int nd = in_sizes[0];        // N*D
    const int n  = nd / D;             // N
    const int E  = in_sizes[3];
    const int nbuk  = (n + RPBUK - 1) / RPBUK;
    const int nblkE = (E + EPB - 1) / EPB;

    char* wsb = (char*)d_ws;
    float* A  = (float*)wsb;                                   // D*D
    float* Lg = A + D * D;                                     // D*D
    float* Mg = Lg + D * D;                                    // D*D
    size_t off = 3 * (size_t)D * D * sizeof(float);

    int* bcnt  = (int*)(wsb + off); off += NBUK_MAX * sizeof(int);
    int* bbase = (int*)(wsb + off); off += NBUK_MAX * sizeof(int);
    int* gcur  = (int*)(wsb + off); off += NBUK_MAX * sizeof(int);
    off = (off + 15) & ~(size_t)15;
    uint2* buk = (uint2*)(wsb + off); off += (size_t)E * sizeof(uint2);
    off = (off + 15) & ~(size_t)15;
    unsigned short* xb = (unsigned short*)(wsb + off);
    off += (size_t)nd * sizeof(unsigned short);
    off = (off + 15) & ~(size_t)15;
    const size_t need_core = off;
    const size_t need_S    = off + (size_t)nd * sizeof(float);
    const int gemm_grid = (n + RPB - 1) / RPB;

    if (ws_size >= need_core && nbuk <= NBUK_MAX && n < (1 << 20)) {
        float* S = (ws_size >= need_S) ? (float*)(wsb + need_core) : out;
        hipMemsetAsync(bcnt, 0, NBUK_MAX * sizeof(int), stream);
        count_bucket_kernel<<<nblkE, 256, 0, stream>>>(ar, bcnt, E, nbuk);
        cvt_bf16_kernel<<<(nd / 8 + 255) / 256, 256, 0, stream>>>(x, xb, nd);
        wtw_kernel<<<D * D / 256, 256, 0, stream>>>(W, A);
        scan_bucket_kernel<<<1, 1024, 0, stream>>>(bcnt, bbase, gcur, nbuk);
        partition_kernel<<<nblkE, 256, 0, stream>>>(ar, ac, av, gcur, buk, E, nbuk);
        chol_factor_kernel<<<1, 256, 0, stream>>>(A, Lg);
        solve_m_kernel<<<D, 64, 0, stream>>>(Lg, W, lp, Mg);
        spmm_bucket_kernel<<<nbuk, 256, 0, stream>>>(xb, h0, buk, bbase, gcur, S, n);
        gemm_tanh_kernel<<<gemm_grid, 256, 0, stream>>>(S, Mg, out, n);
    } else {
        float* hi = out;
        hipMemsetAsync(hi, 0, (size_t)nd * sizeof(float), stream);
        wtw_kernel<<<D * D / 256, 256, 0, stream>>>(W, A);
        spmm_atomic_kernel<<<(int)(((size_t)E * 32 + 255) / 256), 256, 0, stream>>>(x, av, ar, ac, hi, E);
        chol_factor_kernel<<<1, 256, 0, stream>>>(A, Lg);
        solve_m_kernel<<<D, 64, 0, stream>>>(Lg, W, lp, Mg);
        blend_kernel<<<(nd / 4 + 255) / 256, 256, 0, stream>>>(hi, h0, hi, nd / 4);
        gemm_tanh_kernel<<<gemm_grid, 256, 0, stream>>>(hi, Mg, out, n);
    }
}

// Round 9
// 345.038 us; speedup vs baseline: 4.5716x; 4.5716x over previous
//
#include <hip/hip_runtime.h>
#include <math.h>

#define D 128
#define NB 16           // Cholesky panel width
#define RPB 64          // rows per block in the GEMM kernel
#define NBUK_MAX 1024   // max buckets (n <= 131072)
#define RPBUK 128       // rows per bucket
#define EPB 16384       // edges per partition block
#define ALPHA 0.1f
#define LAMDA 0.5f

// ---------------- K1: A = W^T W + 1e-4 I  (tiny) ----------------
__global__ __launch_bounds__(256) void wtw_kernel(const float* __restrict__ W,
                                                  float* __restrict__ A) {
    int idx = blockIdx.x * blockDim.x + threadIdx.x;
    int i = idx >> 7, j = idx & (D - 1);
    float acc = (i == j) ? 1e-4f : 0.0f;
#pragma unroll 4
    for (int k = 0; k < D; ++k) acc = fmaf(W[k * D + i], W[k * D + j], acc);
    A[idx] = acc;
}

// ---------------- K2a: one-block BLOCKED Cholesky (NB=16) ----------------
__global__ __launch_bounds__(256) void chol_factor_kernel(const float* __restrict__ A_in,
                                                          float* __restrict__ Lg) {
    __shared__ float S[D][D];
    __shared__ float dinvS[NB];
    const int tid = threadIdx.x;
    const int tx = tid & 15;
    const int ty = tid >> 4;

    for (int i = tid; i < D * D; i += 256) ((float*)S)[i] = A_in[i];
    __syncthreads();

    for (int s = 0; s < D / NB; ++s) {
        const int b = s * NB;

        for (int k = 0; k < NB; ++k) {
            float dk  = S[b + k][b + k];
            float a_i = S[b + k][b + tx];
            float a_j = S[b + k][b + ty];
            float lkk  = sqrtf(dk);
            float inv  = 1.0f / lkk;
            float invd = inv * inv;
            __syncthreads();
            if (ty == 0) {
                if (tx == k)       { S[b + k][b + k] = lkk; dinvS[k] = inv; }
                else if (tx > k)     S[b + k][b + tx] = a_i * inv;
            }
            if (ty > k && tx >= ty)
                S[b + ty][b + tx] -= a_i * (a_j * invd);
            __syncthreads();
        }

        const int m = D - b - NB;

        if (m > 0 && tid < m) {
            const int r = b + NB + tid;
            float y[NB];
#pragma unroll
            for (int k = 0; k < NB; ++k) y[k] = S[b + k][r];
#pragma unroll
            for (int k = 0; k < NB; ++k) {
                float acc = y[k];
#pragma unroll
                for (int q = 0; q < NB; ++q)
                    if (q < k) acc -= S[b + q][b + k] * y[q];
                y[k] = acc * dinvS[k];
            }
#pragma unroll
            for (int k = 0; k < NB; ++k) S[b + k][r] = y[k];
        }
        __syncthreads();

        const int nt = m >> 4;
        for (int tc = 0; tc < nt; ++tc) {
            for (int tr = tc; tr < nt; ++tr) {
                const int c = b + NB + tc * 16 + ty;
                const int r = b + NB + tr * 16 + tx;
                if (r >= c) {
                    float acc = S[c][r];
#pragma unroll
                    for (int k = 0; k < NB; ++k)
                        acc -= S[b + k][r] * S[b + k][c];
                    S[c][r] = acc;
                }
            }
        }
        __syncthreads();
    }

    for (int i = tid; i < D * D; i += 256) Lg[i] = ((float*)S)[i];
}

// ---------------- K2b: parallel triangular solve + build M ---------------
__global__ __launch_bounds__(64) void solve_m_kernel(const float* __restrict__ Lg,
                                                     const float* __restrict__ W,
                                                     const int* __restrict__ lp,
                                                     float* __restrict__ Mg) {
    __shared__ float Lr[D][D + 1];
    const int lane = threadIdx.x;
    const int c = blockIdx.x;

    for (int j = 0; j < D; ++j) {
        Lr[lane][j]      = Lg[j * D + lane];
        Lr[lane + 64][j] = Lg[j * D + lane + 64];
    }
    __syncthreads();

    const float w_lo = W[c * D + lane];
    const float w_hi = W[c * D + 64 + lane];
    const float dinv_lo = 1.0f / Lr[lane][lane];
    const float dinv_hi = 1.0f / Lr[lane + 64][lane + 64];
    float y_lo = 0.0f, y_hi = 0.0f;

    for (int i = 0; i < D; ++i) {
        float l0 = Lr[i][lane];
        float l1 = Lr[i][lane + 64];
        float p = 0.0f;
        p += (lane < i)      ? l0 * y_lo : 0.0f;
        p += (lane + 64 < i) ? l1 * y_hi : 0.0f;
#pragma unroll
        for (int off = 32; off >= 1; off >>= 1) p += __shfl_xor(p, off);
        if (i < 64) {
            if (lane == i)      y_lo = (w_lo - p) * dinv_lo;
        } else {
            if (lane == i - 64) y_hi = (w_hi - p) * dinv_hi;
        }
    }

    const float th = logf(LAMDA / (float)(*lp) + 1.0f);
    float m_lo = th * y_lo + ((c == lane)      ? (1.0f - th) : 0.0f);
    float m_hi = th * y_hi + ((c == lane + 64) ? (1.0f - th) : 0.0f);
    Mg[c * D + lane]      = m_lo;
    Mg[c * D + 64 + lane] = m_hi;
}

// ---------------- x -> bf16 conversion (RNE) -----------------------------
__global__ __launch_bounds__(256) void cvt_bf16_kernel(const float* __restrict__ x,
                                                       unsigned short* __restrict__ xb,
                                                       int nd) {
    const int base = (blockIdx.x * 256 + threadIdx.x) * 8;
    if (base + 7 < nd) {
        float4 a = *reinterpret_cast<const float4*>(x + base);
        float4 b = *reinterpret_cast<const float4*>(x + base + 4);
        unsigned r[8];
        const float* f = &a.x;
#pragma unroll
        for (int i = 0; i < 4; ++i) {
            unsigned u = __float_as_uint(f[i]);
            r[i] = (u + 0x7FFFu + ((u >> 16) & 1u)) >> 16;
        }
        const float* g = &b.x;
#pragma unroll
        for (int i = 0; i < 4; ++i) {
            unsigned u = __float_as_uint(g[i]);
            r[4 + i] = (u + 0x7FFFu + ((u >> 16) & 1u)) >> 16;
        }
        uint4 o;
        o.x = r[0] | (r[1] << 16);
        o.y = r[2] | (r[3] << 16);
        o.z = r[4] | (r[5] << 16);
        o.w = r[6] | (r[7] << 16);
        *reinterpret_cast<uint4*>(xb + base) = o;
    } else {
        for (int i = 0; i < 8 && base + i < nd; ++i) {
            unsigned u = __float_as_uint(x[base + i]);
            xb[base + i] = (unsigned short)((u + 0x7FFFu + ((u >> 16) & 1u)) >> 16);
        }
    }
}

// ======== Path A: 2-pass counting sort (bucket -> row) ====================
__global__ __launch_bounds__(256) void count_bucket_kernel(const int* __restrict__ rows,
                                                           int* __restrict__ bcnt,
                                                           int E, int nbuk) {
    __shared__ int lcnt[NBUK_MAX];
    const int tid = threadIdx.x;
    const int e0 = blockIdx.x * EPB;
    const int e1 = min(e0 + EPB, E);
    for (int i = tid; i < nbuk; i += 256) lcnt[i] = 0;
    __syncthreads();
    for (int e = e0 + tid * 4; e < e1; e += 1024) {
        if (e + 3 < e1) {
            int4 r = *reinterpret_cast<const int4*>(rows + e);
            atomicAdd(&lcnt[r.x >> 7], 1);
            atomicAdd(&lcnt[r.y >> 7], 1);
            atomicAdd(&lcnt[r.z >> 7], 1);
            atomicAdd(&lcnt[r.w >> 7], 1);
        } else {
            int lim = min(e + 4, e1);
            for (int k = e; k < lim; ++k) atomicAdd(&lcnt[rows[k] >> 7], 1);
        }
    }
    __syncthreads();
    for (int i = tid; i < nbuk; i += 256) {
        int c = lcnt[i];
        if (c) atomicAdd(&bcnt[i], c);
    }
}

__global__ __launch_bounds__(1024) void scan_bucket_kernel(const int* __restrict__ bcnt,
                                                           int* __restrict__ bbase,
                                                           int* __restrict__ gcur,
                                                           int nbuk) {
    __shared__ int ps[1024];
    const int tid = threadIdx.x;
    int v = (tid < nbuk) ? bcnt[tid] : 0;
    ps[tid] = v;
    __syncthreads();
    for (int off = 1; off < 1024; off <<= 1) {
        int t = (tid >= off) ? ps[tid - off] : 0;
        __syncthreads();
        ps[tid] += t;
        __syncthreads();
    }
    if (tid < nbuk) {
        int excl = ps[tid] - v;
        bbase[tid] = excl;
        gcur[tid]  = excl;
    }
}

// Pass 1: partition into 128-row buckets; meta = col | (row&127)<<20.
// Writes are frontier-local (782 moving frontiers), not fully random.
__global__ __launch_bounds__(256) void partition_kernel(const int* __restrict__ rows,
                                                        const int* __restrict__ cols,
                                                        const float* __restrict__ vals,
                                                        int* __restrict__ gcur,
                                                        uint2* __restrict__ buk,
                                                        int E, int nbuk) {
    __shared__ int lcnt[NBUK_MAX];
    __shared__ int lbase[NBUK_MAX];
    __shared__ int loff[NBUK_MAX];
    const int tid = threadIdx.x;
    const int e0 = blockIdx.x * EPB;
    const int e1 = min(e0 + EPB, E);
    for (int i = tid; i < nbuk; i += 256) { lcnt[i] = 0; loff[i] = 0; }
    __syncthreads();
    for (int e = e0 + tid * 4; e < e1; e += 1024) {
        if (e + 3 < e1) {
            int4 r = *reinterpret_cast<const int4*>(rows + e);
            atomicAdd(&lcnt[r.x >> 7], 1);
            atomicAdd(&lcnt[r.y >> 7], 1);
            atomicAdd(&lcnt[r.z >> 7], 1);
            atomicAdd(&lcnt[r.w >> 7], 1);
        } else {
            int lim = min(e + 4, e1);
            for (int k = e; k < lim; ++k) atomicAdd(&lcnt[rows[k] >> 7], 1);
        }
    }
    __syncthreads();
    for (int i = tid; i < nbuk; i += 256) {
        int c = lcnt[i];
        if (c) lbase[i] = atomicAdd(&gcur[i], c);
    }
    __syncthreads();
    for (int e = e0 + tid * 4; e < e1; e += 1024) {
        if (e + 3 < e1) {
            int4 r = *reinterpret_cast<const int4*>(rows + e);
            int4 c = *reinterpret_cast<const int4*>(cols + e);
            float4 v = *reinterpret_cast<const float4*>(vals + e);
            {
                int b = r.x >> 7; int li = atomicAdd(&loff[b], 1);
                buk[lbase[b] + li] = make_uint2((unsigned)c.x | ((unsigned)(r.x & 127) << 20), __float_as_uint(v.x));
            }
            {
                int b = r.y >> 7; int li = atomicAdd(&loff[b], 1);
                buk[lbase[b] + li] = make_uint2((unsigned)c.y | ((unsigned)(r.y & 127) << 20), __float_as_uint(v.y));
            }
            {
                int b = r.z >> 7; int li = atomicAdd(&loff[b], 1);
                buk[lbase[b] + li] = make_uint2((unsigned)c.z | ((unsigned)(r.z & 127) << 20), __float_as_uint(v.z));
            }
            {
                int b = r.w >> 7; int li = atomicAdd(&loff[b], 1);
                buk[lbase[b] + li] = make_uint2((unsigned)c.w | ((unsigned)(r.w & 127) << 20), __float_as_uint(v.w));
            }
        } else {
            int lim = min(e + 4, e1);
            for (int k = e; k < lim; ++k) {
                int rr = rows[k];
                int b = rr >> 7; int li = atomicAdd(&loff[b], 1);
                buk[lbase[b] + li] = make_uint2((unsigned)cols[k] | ((unsigned)(rr & 127) << 20), __float_as_uint(vals[k]));
            }
        }
    }
}

// Pass 2: within each bucket, sort edges by local row (LDS hist + scan) and
// write row-contiguous CSR into the bucket's OWN 16 KB window (L2-local).
// Also emits rp[r] = end-of-row offsets for the gather.
__global__ __launch_bounds__(256) void bucket_to_csr_kernel(const uint2* __restrict__ buk,
                                                            const int* __restrict__ bbase,
                                                            const int* __restrict__ bend,
                                                            uint2* __restrict__ csr,
                                                            int* __restrict__ rp, int n) {
    __shared__ int lcnt[RPBUK];
    __shared__ int lofs[RPBUK];
    const int tid = threadIdx.x;
    const int b = blockIdx.x;
    const int start = bbase[b], end = bend[b];

    if (tid < RPBUK) lcnt[tid] = 0;
    __syncthreads();
    for (int j = start + tid; j < end; j += 256)
        atomicAdd(&lcnt[buk[j].x >> 20], 1);
    __syncthreads();
    if (tid < RPBUK) lofs[tid] = lcnt[tid];
    __syncthreads();
    for (int off = 1; off < RPBUK; off <<= 1) {
        int v = (tid < RPBUK && tid >= off) ? lofs[tid - off] : 0;
        __syncthreads();
        if (tid < RPBUK) lofs[tid] += v;   // inclusive scan
        __syncthreads();
    }
    if (tid < RPBUK) {
        int r = b * RPBUK + tid;
        if (r < n) rp[r] = start + lofs[tid];   // end offset of row r
        lofs[tid] -= lcnt[tid];                 // -> exclusive cursor
    }
    __syncthreads();
    for (int j = start + tid; j < end; j += 256) {
        uint2 e = buk[j];
        int rl = e.x >> 20;
        int pos = atomicAdd(&lofs[rl], 1);
        csr[start + pos] = make_uint2(e.x & 0xFFFFFu, e.y);
    }
}

// ======== Path B CSR build (round-6 proven): hist -> 3-phase scan -> scatter
__global__ __launch_bounds__(256) void hist_kernel(const int* __restrict__ rows,
                                                   int* __restrict__ cnt, int E) {
    int e = blockIdx.x * blockDim.x + threadIdx.x;
    if (e < E) atomicAdd(&cnt[rows[e]], 1);
}

__global__ __launch_bounds__(256) void scan_p1_kernel(const int* __restrict__ cnt,
                                                      int* __restrict__ bsum, int n) {
    const int tid = threadIdx.x;
    const int base = blockIdx.x * 1024 + tid * 4;
    int s = 0;
    if (base + 3 < n) {
        int4 v = *reinterpret_cast<const int4*>(cnt + base);
        s = v.x + v.y + v.z + v.w;
    } else {
        for (int j = 0; j < 4; ++j) if (base + j < n) s += cnt[base + j];
    }
#pragma unroll
    for (int off = 32; off >= 1; off >>= 1) s += __shfl_xor(s, off);
    __shared__ int wsum[4];
    if ((tid & 63) == 0) wsum[tid >> 6] = s;
    __syncthreads();
    if (tid == 0) bsum[blockIdx.x] = wsum[0] + wsum[1] + wsum[2] + wsum[3];
}

__global__ __launch_bounds__(256) void scan_p2_kernel(int* __restrict__ bsum, int nb) {
    __shared__ int ps[256];
    const int tid = threadIdx.x;
    int carry = 0;
    for (int base = 0; base < nb; base += 256) {
        int idx = base + tid;
        int v = (idx < nb) ? bsum[idx] : 0;
        ps[tid] = v;
        __syncthreads();
        for (int off = 1; off < 256; off <<= 1) {
            int t = (tid >= off) ? ps[tid - off] : 0;
            __syncthreads();
            ps[tid] += t;
            __syncthreads();
        }
        if (idx < nb) bsum[idx] = carry + ps[tid] - v;
        int total = ps[255];
        __syncthreads();
        carry += total;
    }
}

__global__ __launch_bounds__(256) void scan_p3_kernel(int* __restrict__ rp,
                                                      const int* __restrict__ bsum,
                                                      int n) {
    const int tid = threadIdx.x;
    const int lane = tid & 63;
    const int w = tid >> 6;
    const int base = blockIdx.x * 1024 + tid * 4;

    int4 v = make_int4(0, 0, 0, 0);
    if (base + 3 < n) {
        v = *reinterpret_cast<const int4*>(rp + base);
    } else {
        if (base + 0 < n) v.x = rp[base + 0];
        if (base + 1 < n) v.y = rp[base + 1];
        if (base + 2 < n) v.z = rp[base + 2];
        if (base + 3 < n) v.w = rp[base + 3];
    }
    int s = v.x + v.y + v.z + v.w;

    int inc = s;
#pragma unroll
    for (int off = 1; off < 64; off <<= 1) {
        int t = __shfl_up(inc, off);
        if (lane >= off) inc += t;
    }
    __shared__ int wsum[4];
    if (lane == 63) wsum[w] = inc;
    __syncthreads();
    int woff = 0;
    for (int i = 0; i < w; ++i) woff += wsum[i];

    int excl = bsum[blockIdx.x] + woff + inc - s;
    int4 o;
    o.x = excl;
    o.y = o.x + v.x;
    o.z = o.y + v.y;
    o.w = o.z + v.z;
    if (base + 3 < n) {
        *reinterpret_cast<int4*>(rp + base) = o;
    } else {
        if (base + 0 < n) rp[base + 0] = o.x;
        if (base + 1 < n) rp[base + 1] = o.y;
        if (base + 2 < n) rp[base + 2] = o.z;
        if (base + 3 < n) rp[base + 3] = o.w;
    }
}

__global__ __launch_bounds__(256) void scatter_kernel(const float* __restrict__ vals,
                                                      const int* __restrict__ rows,
                                                      const int* __restrict__ cols,
                                                      int* __restrict__ rp,
                                                      uint2* __restrict__ csr, int E) {
    int e = blockIdx.x * blockDim.x + threadIdx.x;
    if (e >= E) return;
    int r = rows[e];
    int pos = atomicAdd(&rp[r], 1);
    csr[pos] = make_uint2((unsigned)cols[e], __float_as_uint(vals[e]));
}

// ---------------- K3: bf16 gather SpMM + fused support scale -------------
__global__ __launch_bounds__(256) void spmm_gather_bf16_kernel(
        const unsigned short* __restrict__ xb,
        const float* __restrict__ h0,
        const uint2* __restrict__ csr,
        const int* __restrict__ rp,
        float* __restrict__ S, int n) {
    const int tid = threadIdx.x;
    const int r = blockIdx.x * 16 + (tid >> 4);
    if (r >= n) return;
    const int q = tid & 15;            // elems 8q .. 8q+7
    const int start = (r == 0) ? 0 : rp[r - 1];
    const int end = rp[r];

    float acc[8] = {};
    int j = start;
    for (; j + 1 < end; j += 2) {
        uint2 p0 = csr[j];
        uint2 p1 = csr[j + 1];
        float v0 = __uint_as_float(p0.y);
        float v1 = __uint_as_float(p1.y);
        uint4 a = *reinterpret_cast<const uint4*>(xb + (size_t)p0.x * D + q * 8);
        uint4 b = *reinterpret_cast<const uint4*>(xb + (size_t)p1.x * D + q * 8);
        const unsigned* aw = &a.x;
        const unsigned* bw = &b.x;
#pragma unroll
        for (int t = 0; t < 4; ++t) {
            float alo = __uint_as_float(aw[t] << 16);
            float ahi = __uint_as_float(aw[t] & 0xffff0000u);
            acc[2 * t]     = fmaf(v0, alo, acc[2 * t]);
            acc[2 * t + 1] = fmaf(v0, ahi, acc[2 * t + 1]);
            float blo = __uint_as_float(bw[t] << 16);
            float bhi = __uint_as_float(bw[t] & 0xffff0000u);
            acc[2 * t]     = fmaf(v1, blo, acc[2 * t]);
            acc[2 * t + 1] = fmaf(v1, bhi, acc[2 * t + 1]);
        }
    }
    if (j < end) {
        uint2 p0 = csr[j];
        float v0 = __uint_as_float(p0.y);
        uint4 a = *reinterpret_cast<const uint4*>(xb + (size_t)p0.x * D + q * 8);
        const unsigned* aw = &a.x;
#pragma unroll
        for (int t = 0; t < 4; ++t) {
            float alo = __uint_as_float(aw[t] << 16);
            float ahi = __uint_as_float(aw[t] & 0xffff0000u);
            acc[2 * t]     = fmaf(v0, alo, acc[2 * t]);
            acc[2 * t + 1] = fmaf(v0, ahi, acc[2 * t + 1]);
        }
    }

    const float4 hb0 = *reinterpret_cast<const float4*>(h0 + (size_t)r * D + q * 8);
    const float4 hb1 = *reinterpret_cast<const float4*>(h0 + (size_t)r * D + q * 8 + 4);
    float4 s0, s1;
    s0.x = 0.9f * acc[0] + 0.1f * hb0.x;
    s0.y = 0.9f * acc[1] + 0.1f * hb0.y;
    s0.z = 0.9f * acc[2] + 0.1f * hb0.z;
    s0.w = 0.9f * acc[3] + 0.1f * hb0.w;
    s1.x = 0.9f * acc[4] + 0.1f * hb1.x;
    s1.y = 0.9f * acc[5] + 0.1f * hb1.y;
    s1.z = 0.9f * acc[6] + 0.1f * hb1.z;
    s1.w = 0.9f * acc[7] + 0.1f * hb1.w;
    *reinterpret_cast<float4*>(S + (size_t)r * D + q * 8)     = s0;
    *reinterpret_cast<float4*>(S + (size_t)r * D + q * 8 + 4) = s1;
}

// -------- Fallback (atomic scatter) if workspace is too small -------------
__global__ __launch_bounds__(256) void spmm_atomic_kernel(const float* __restrict__ x,
                                                          const float* __restrict__ vals,
                                                          const int* __restrict__ rows,
                                                          const int* __restrict__ cols,
                                                          float* __restrict__ hi, int E) {
    int tid = blockIdx.x * blockDim.x + threadIdx.x;
    int e = tid >> 5;
    if (e >= E) return;
    int q = tid & 31;
    float v = vals[e];
    int c = cols[e];
    int r = rows[e];
    const float4 xv = *reinterpret_cast<const float4*>(x + (size_t)c * D + q * 4);
    float* h = hi + (size_t)r * D + q * 4;
    unsafeAtomicAdd(h + 0, v * xv.x);
    unsafeAtomicAdd(h + 1, v * xv.y);
    unsafeAtomicAdd(h + 2, v * xv.z);
    unsafeAtomicAdd(h + 3, v * xv.w);
}

__global__ __launch_bounds__(256) void blend_kernel(const float* __restrict__ hi,
                                                    const float* __restrict__ h0,
                                                    float* __restrict__ S, int nd4) {
    int i = blockIdx.x * blockDim.x + threadIdx.x;
    if (i >= nd4) return;
    float4 a = reinterpret_cast<const float4*>(hi)[i];
    float4 b = reinterpret_cast<const float4*>(h0)[i];
    float4 s;
    s.x = 0.9f * a.x + 0.1f * b.x;
    s.y = 0.9f * a.y + 0.1f * b.y;
    s.z = 0.9f * a.z + 0.1f * b.z;
    s.w = 0.9f * a.w + 0.1f * b.w;
    reinterpret_cast<float4*>(S)[i] = s;
}

// ---------------- K4: out = tanh(S @ M), 64 rows/block, 4x8/thread -------
__global__ __launch_bounds__(256) void gemm_tanh_kernel(const float* __restrict__ S,
                                                        const float* __restrict__ Mg,
                                                        float* __restrict__ out, int n) {
    __shared__ float Ms[64][D];
    __shared__ float Ss[RPB][D + 1];
    const int tid = threadIdx.x;
    const int r0  = blockIdx.x * RPB;

    for (int i = tid; i < RPB * D / 4; i += 256) {
        int rr = (i * 4) / D, cc = (i * 4) & (D - 1);
        int r = r0 + rr;
        float4 a = (r < n) ? *reinterpret_cast<const float4*>(S + (size_t)r * D + cc)
                           : make_float4(0.f, 0.f, 0.f, 0.f);
        Ss[rr][cc + 0] = a.x;
        Ss[rr][cc + 1] = a.y;
        Ss[rr][cc + 2] = a.z;
        Ss[rr][cc + 3] = a.w;
    }

    const int tc = tid & 15;
    const int tr = tid >> 4;
    float acc[4][8] = {};

    for (int kb = 0; kb < 2; ++kb) {
        __syncthreads();
        for (int i = tid; i < 64 * D / 4; i += 256)
            reinterpret_cast<float4*>(&Ms[0][0])[i] =
                reinterpret_cast<const float4*>(Mg + kb * 64 * D)[i];
        __syncthreads();
#pragma unroll 4
        for (int kk = 0; kk < 64; ++kk) {
            int k = kb * 64 + kk;
            float4 b0 = *reinterpret_cast<const float4*>(&Ms[kk][tc * 4]);
            float4 b1 = *reinterpret_cast<const float4*>(&Ms[kk][64 + tc * 4]);
#pragma unroll
            for (int m = 0; m < 4; ++m) {
                float a = Ss[4 * tr + m][k];
                acc[m][0] = fmaf(a, b0.x, acc[m][0]);
                acc[m][1] = fmaf(a, b0.y, acc[m][1]);
                acc[m][2] = fmaf(a, b0.z, acc[m][2]);
                acc[m][3] = fmaf(a, b0.w, acc[m][3]);
                acc[m][4] = fmaf(a, b1.x, acc[m][4]);
                acc[m][5] = fmaf(a, b1.y, acc[m][5]);
                acc[m][6] = fmaf(a, b1.z, acc[m][6]);
                acc[m][7] = fmaf(a, b1.w, acc[m][7]);
            }
        }
    }

#pragma unroll
    for (int m = 0; m < 4; ++m) {
        int r = r0 + 4 * tr + m;
        if (r >= n) continue;
        float4 o0, o1;
        o0.x = tanhf(acc[m][0]); o0.y = tanhf(acc[m][1]);
        o0.z = tanhf(acc[m][2]); o0.w = tanhf(acc[m][3]);
        o1.x = tanhf(acc[m][4]); o1.y = tanhf(acc[m][5]);
        o1.z = tanhf(acc[m][6]); o1.w = tanhf(acc[m][7]);
        *reinterpret_cast<float4*>(out + (size_t)r * D + tc * 4)      = o0;
        *reinterpret_cast<float4*>(out + (size_t)r * D + 64 + tc * 4) = o1;
    }
}

extern "C" void kernel_launch(void* const* d_in, const int* in_sizes, int n_in,
                              void* d_out, int out_size, void* d_ws, size_t ws_size,
                              hipStream_t stream) {
    const float* x  = (const float*)d_in[0];
    const float* h0 = (const float*)d_in[1];
    const float* W  = (const float*)d_in[2];
    const float* av = (const float*)d_in[3];
    const int*   ar = (const int*)d_in[4];
    const int*   ac = (const int*)d_in[5];
    const int*   lp = (const int*)d_in[6];
    float* out = (float*)d_out;

    const int nd = in_sizes[0];        // N*D
    const int n  = nd / D;             // N
    const int E  = in_sizes[3];
    const int nbuk  = (n + RPBUK - 1) / RPBUK;
    const int nblkE = (E + EPB - 1) / EPB;
    const int nb = (n + 1023) / 1024;  // path-B scan blocks

    char* wsb = (char*)d_ws;
    float* A  = (float*)wsb;                                   // D*D
    float* Lg = A + D * D;                                     // D*D
    float* Mg = Lg + D * D;                                    // D*D
    size_t off = 3 * (size_t)D * D * sizeof(float);

    int* bcnt  = (int*)(wsb + off); off += NBUK_MAX * sizeof(int);  // also bsum (path B)
    int* bbase = (int*)(wsb + off); off += NBUK_MAX * sizeof(int);
    int* gcur  = (int*)(wsb + off); off += NBUK_MAX * sizeof(int);
    off = (off + 15) & ~(size_t)15;
    int* rp = (int*)(wsb + off); off += (size_t)n * sizeof(int);
    off = (off + 15) & ~(size_t)15;
    uint2* csr = (uint2*)(wsb + off); off += (size_t)E * sizeof(uint2);
    off = (off + 15) & ~(size_t)15;
    const size_t off_after_csr = off;
    uint2* buk = (uint2*)(wsb + off);                          // path A only
    size_t off_a = off + (size_t)E * sizeof(uint2);
    off_a = (off_a + 15) & ~(size_t)15;

    const int gemm_grid = (n + RPB - 1) / RPB;

    // ---- Path A: bucket sort CSR build (needs buk) ----
    {
        size_t o = off_a;
        unsigned short* xb = (unsigned short*)(wsb + o);
        o += (size_t)nd * sizeof(unsigned short);
        o = (o + 15) & ~(size_t)15;
        const size_t need_core = o;
        const size_t need_S = o + (size_t)nd * sizeof(float);
        if (ws_size >= need_core && nbuk <= NBUK_MAX && n < (1 << 20)) {
            float* S = (ws_size >= need_S) ? (float*)(wsb + need_core) : out;
            hipMemsetAsync(bcnt, 0, NBUK_MAX * sizeof(int), stream);
            count_bucket_kernel<<<nblkE, 256, 0, stream>>>(ar, bcnt, E, nbuk);
            cvt_bf16_kernel<<<(nd / 8 + 255) / 256, 256, 0, stream>>>(x, xb, nd);
            wtw_kernel<<<D * D / 256, 256, 0, stream>>>(W, A);
            scan_bucket_kernel<<<1, 1024, 0, stream>>>(bcnt, bbase, gcur, nbuk);
            partition_kernel<<<nblkE, 256, 0, stream>>>(ar, ac, av, gcur, buk, E, nbuk);
            bucket_to_csr_kernel<<<nbuk, 256, 0, stream>>>(buk, bbase, gcur, csr, rp, n);
            chol_factor_kernel<<<1, 256, 0, stream>>>(A, Lg);
            solve_m_kernel<<<D, 64, 0, stream>>>(Lg, W, lp, Mg);
            spmm_gather_bf16_kernel<<<(n + 15) / 16, 256, 0, stream>>>(xb, h0, csr, rp, S, n);
            gemm_tanh_kernel<<<gemm_grid, 256, 0, stream>>>(S, Mg, out, n);
            return;
        }
    }

    // ---- Path B: round-6 CSR build (hist/scan/scatter) ----
    {
        size_t o = off_after_csr;
        unsigned short* xb = (unsigned short*)(wsb + o);
        o += (size_t)nd * sizeof(unsigned short);
        o = (o + 15) & ~(size_t)15;
        const size_t need_core = o;
        const size_t need_S = o + (size_t)nd * sizeof(float);
        if (ws_size >= need_core && nb <= NBUK_MAX && n < (1 << 20)) {
            float* S = (ws_size >= need_S) ? (float*)(wsb + need_core) : out;
            hipMemsetAsync(rp, 0, (size_t)n * sizeof(int), stream);
            hist_kernel<<<(E + 255) / 256, 256, 0, stream>>>(ar, rp, E);
            cvt_bf16_kernel<<<(nd / 8 + 255) / 256, 256, 0, stream>>>(x, xb, nd);
            wtw_kernel<<<D * D / 256, 256, 0, stream>>>(W, A);
            scan_p1_kernel<<<nb, 256, 0, stream>>>(rp, bcnt, n);
            scan_p2_kernel<<<1, 256, 0, stream>>>(bcnt, nb);
            scan_p3_kernel<<<nb, 256, 0, stream>>>(rp, bcnt, n);
            scatter_kernel<<<(E + 255) / 256, 256, 0, stream>>>(av, ar, ac, rp, csr, E);
            chol_factor_kernel<<<1, 256, 0, stream>>>(A, Lg);
            solve_m_kernel<<<D, 64, 0, stream>>>(Lg, W, lp, Mg);
            spmm_gather_bf16_kernel<<<(n + 15) / 16, 256, 0, stream>>>(xb, h0, csr, rp, S, n);
            gemm_tanh_kernel<<<gemm_grid, 256, 0, stream>>>(S, Mg, out, n);
            return;
        }
    }

    // ---- Path C: minimal-workspace fallback ----
    {
        float* hi = out;
        hipMemsetAsync(hi, 0, (size_t)nd * sizeof(float), stream);
        wtw_kernel<<<D * D / 256, 256, 0, stream>>>(W, A);
        spmm_atomic_kernel<<<(int)(((size_t)E * 32 + 255) / 256), 256, 0, stream>>>(x, av, ar, ac, hi, E);
        chol_factor_kernel<<<1, 256, 0, stream>>>(A, Lg);
        solve_m_kernel<<<D, 64, 0, stream>>>(Lg, W, lp, Mg);
        blend_kernel<<<(nd / 4 + 255) / 256, 256, 0, stream>>>(hi, h0, hi, nd / 4);
        gemm_tanh_kernel<<<gemm_grid, 256, 0, stream>>>(hi, Mg, out, n);
    }
}

// Round 10
// 323.225 us; speedup vs baseline: 4.8801x; 1.0675x over previous
//
#include <hip/hip_runtime.h>
#include <math.h>

#define D 128
#define NB 16           // Cholesky panel width
#define RPB 64          // rows per block in the fused SpMM+GEMM kernel
#define NBUK_MAX 1024   // max buckets (n <= 131072)
#define RPBUK 128       // rows per bucket
#define EPB 16384       // edges per partition block
#define ALPHA 0.1f
#define LAMDA 0.5f

// ---------------- K1: A = W^T W + 1e-4 I  (tiny) ----------------
__global__ __launch_bounds__(256) void wtw_kernel(const float* __restrict__ W,
                                                  float* __restrict__ A) {
    int idx = blockIdx.x * blockDim.x + threadIdx.x;
    int i = idx >> 7, j = idx & (D - 1);
    float acc = (i == j) ? 1e-4f : 0.0f;
#pragma unroll 4
    for (int k = 0; k < D; ++k) acc = fmaf(W[k * D + i], W[k * D + j], acc);
    A[idx] = acc;
}

// ---------------- K2a: one-block BLOCKED Cholesky (NB=16) ----------------
__global__ __launch_bounds__(256) void chol_factor_kernel(const float* __restrict__ A_in,
                                                          float* __restrict__ Lg) {
    __shared__ float S[D][D];
    __shared__ float dinvS[NB];
    const int tid = threadIdx.x;
    const int tx = tid & 15;
    const int ty = tid >> 4;

    for (int i = tid; i < D * D; i += 256) ((float*)S)[i] = A_in[i];
    __syncthreads();

    for (int s = 0; s < D / NB; ++s) {
        const int b = s * NB;

        for (int k = 0; k < NB; ++k) {
            float dk  = S[b + k][b + k];
            float a_i = S[b + k][b + tx];
            float a_j = S[b + k][b + ty];
            float lkk  = sqrtf(dk);
            float inv  = 1.0f / lkk;
            float invd = inv * inv;
            __syncthreads();
            if (ty == 0) {
                if (tx == k)       { S[b + k][b + k] = lkk; dinvS[k] = inv; }
                else if (tx > k)     S[b + k][b + tx] = a_i * inv;
            }
            if (ty > k && tx >= ty)
                S[b + ty][b + tx] -= a_i * (a_j * invd);
            __syncthreads();
        }

        const int m = D - b - NB;

        if (m > 0 && tid < m) {
            const int r = b + NB + tid;
            float y[NB];
#pragma unroll
            for (int k = 0; k < NB; ++k) y[k] = S[b + k][r];
#pragma unroll
            for (int k = 0; k < NB; ++k) {
                float acc = y[k];
#pragma unroll
                for (int q = 0; q < NB; ++q)
                    if (q < k) acc -= S[b + q][b + k] * y[q];
                y[k] = acc * dinvS[k];
            }
#pragma unroll
            for (int k = 0; k < NB; ++k) S[b + k][r] = y[k];
        }
        __syncthreads();

        const int nt = m >> 4;
        for (int tc = 0; tc < nt; ++tc) {
            for (int tr = tc; tr < nt; ++tr) {
                const int c = b + NB + tc * 16 + ty;
                const int r = b + NB + tr * 16 + tx;
                if (r >= c) {
                    float acc = S[c][r];
#pragma unroll
                    for (int k = 0; k < NB; ++k)
                        acc -= S[b + k][r] * S[b + k][c];
                    S[c][r] = acc;
                }
            }
        }
        __syncthreads();
    }

    for (int i = tid; i < D * D; i += 256) Lg[i] = ((float*)S)[i];
}

// ---------------- K2b: parallel triangular solve + build M ---------------
__global__ __launch_bounds__(64) void solve_m_kernel(const float* __restrict__ Lg,
                                                     const float* __restrict__ W,
                                                     const int* __restrict__ lp,
                                                     float* __restrict__ Mg) {
    __shared__ float Lr[D][D + 1];
    const int lane = threadIdx.x;
    const int c = blockIdx.x;

    for (int j = 0; j < D; ++j) {
        Lr[lane][j]      = Lg[j * D + lane];
        Lr[lane + 64][j] = Lg[j * D + lane + 64];
    }
    __syncthreads();

    const float w_lo = W[c * D + lane];
    const float w_hi = W[c * D + 64 + lane];
    const float dinv_lo = 1.0f / Lr[lane][lane];
    const float dinv_hi = 1.0f / Lr[lane + 64][lane + 64];
    float y_lo = 0.0f, y_hi = 0.0f;

    for (int i = 0; i < D; ++i) {
        float l0 = Lr[i][lane];
        float l1 = Lr[i][lane + 64];
        float p = 0.0f;
        p += (lane < i)      ? l0 * y_lo : 0.0f;
        p += (lane + 64 < i) ? l1 * y_hi : 0.0f;
#pragma unroll
        for (int off = 32; off >= 1; off >>= 1) p += __shfl_xor(p, off);
        if (i < 64) {
            if (lane == i)      y_lo = (w_lo - p) * dinv_lo;
        } else {
            if (lane == i - 64) y_hi = (w_hi - p) * dinv_hi;
        }
    }

    const float th = logf(LAMDA / (float)(*lp) + 1.0f);
    float m_lo = th * y_lo + ((c == lane)      ? (1.0f - th) : 0.0f);
    float m_hi = th * y_hi + ((c == lane + 64) ? (1.0f - th) : 0.0f);
    Mg[c * D + lane]      = m_lo;
    Mg[c * D + 64 + lane] = m_hi;
}

// ---------------- x -> bf16 conversion (RNE) -----------------------------
__global__ __launch_bounds__(256) void cvt_bf16_kernel(const float* __restrict__ x,
                                                       unsigned short* __restrict__ xb,
                                                       int nd) {
    const int base = (blockIdx.x * 256 + threadIdx.x) * 8;
    if (base + 7 < nd) {
        float4 a = *reinterpret_cast<const float4*>(x + base);
        float4 b = *reinterpret_cast<const float4*>(x + base + 4);
        unsigned r[8];
        const float* f = &a.x;
#pragma unroll
        for (int i = 0; i < 4; ++i) {
            unsigned u = __float_as_uint(f[i]);
            r[i] = (u + 0x7FFFu + ((u >> 16) & 1u)) >> 16;
        }
        const float* g = &b.x;
#pragma unroll
        for (int i = 0; i < 4; ++i) {
            unsigned u = __float_as_uint(g[i]);
            r[4 + i] = (u + 0x7FFFu + ((u >> 16) & 1u)) >> 16;
        }
        uint4 o;
        o.x = r[0] | (r[1] << 16);
        o.y = r[2] | (r[3] << 16);
        o.z = r[4] | (r[5] << 16);
        o.w = r[6] | (r[7] << 16);
        *reinterpret_cast<uint4*>(xb + base) = o;
    } else {
        for (int i = 0; i < 8 && base + i < nd; ++i) {
            unsigned u = __float_as_uint(x[base + i]);
            xb[base + i] = (unsigned short)((u + 0x7FFFu + ((u >> 16) & 1u)) >> 16);
        }
    }
}

// ======== CSR build: 2-pass counting sort (bucket -> row) ================
__global__ __launch_bounds__(256) void count_bucket_kernel(const int* __restrict__ rows,
                                                           int* __restrict__ bcnt,
                                                           int E, int nbuk) {
    __shared__ int lcnt[NBUK_MAX];
    const int tid = threadIdx.x;
    const int e0 = blockIdx.x * EPB;
    const int e1 = min(e0 + EPB, E);
    for (int i = tid; i < nbuk; i += 256) lcnt[i] = 0;
    __syncthreads();
    for (int e = e0 + tid * 4; e < e1; e += 1024) {
        if (e + 3 < e1) {
            int4 r = *reinterpret_cast<const int4*>(rows + e);
            atomicAdd(&lcnt[r.x >> 7], 1);
            atomicAdd(&lcnt[r.y >> 7], 1);
            atomicAdd(&lcnt[r.z >> 7], 1);
            atomicAdd(&lcnt[r.w >> 7], 1);
        } else {
            int lim = min(e + 4, e1);
            for (int k = e; k < lim; ++k) atomicAdd(&lcnt[rows[k] >> 7], 1);
        }
    }
    __syncthreads();
    for (int i = tid; i < nbuk; i += 256) {
        int c = lcnt[i];
        if (c) atomicAdd(&bcnt[i], c);
    }
}

__global__ __launch_bounds__(1024) void scan_bucket_kernel(const int* __restrict__ bcnt,
                                                           int* __restrict__ bbase,
                                                           int* __restrict__ gcur,
                                                           int nbuk) {
    __shared__ int ps[1024];
    const int tid = threadIdx.x;
    int v = (tid < nbuk) ? bcnt[tid] : 0;
    ps[tid] = v;
    __syncthreads();
    for (int off = 1; off < 1024; off <<= 1) {
        int t = (tid >= off) ? ps[tid - off] : 0;
        __syncthreads();
        ps[tid] += t;
        __syncthreads();
    }
    if (tid < nbuk) {
        int excl = ps[tid] - v;
        bbase[tid] = excl;
        gcur[tid]  = excl;
    }
}

__global__ __launch_bounds__(256) void partition_kernel(const int* __restrict__ rows,
                                                        const int* __restrict__ cols,
                                                        const float* __restrict__ vals,
                                                        int* __restrict__ gcur,
                                                        uint2* __restrict__ buk,
                                                        int E, int nbuk) {
    __shared__ int lcnt[NBUK_MAX];
    __shared__ int lbase[NBUK_MAX];
    __shared__ int loff[NBUK_MAX];
    const int tid = threadIdx.x;
    const int e0 = blockIdx.x * EPB;
    const int e1 = min(e0 + EPB, E);
    for (int i = tid; i < nbuk; i += 256) { lcnt[i] = 0; loff[i] = 0; }
    __syncthreads();
    for (int e = e0 + tid * 4; e < e1; e += 1024) {
        if (e + 3 < e1) {
            int4 r = *reinterpret_cast<const int4*>(rows + e);
            atomicAdd(&lcnt[r.x >> 7], 1);
            atomicAdd(&lcnt[r.y >> 7], 1);
            atomicAdd(&lcnt[r.z >> 7], 1);
            atomicAdd(&lcnt[r.w >> 7], 1);
        } else {
            int lim = min(e + 4, e1);
            for (int k = e; k < lim; ++k) atomicAdd(&lcnt[rows[k] >> 7], 1);
        }
    }
    __syncthreads();
    for (int i = tid; i < nbuk; i += 256) {
        int c = lcnt[i];
        if (c) lbase[i] = atomicAdd(&gcur[i], c);
    }
    __syncthreads();
    for (int e = e0 + tid * 4; e < e1; e += 1024) {
        if (e + 3 < e1) {
            int4 r = *reinterpret_cast<const int4*>(rows + e);
            int4 c = *reinterpret_cast<const int4*>(cols + e);
            float4 v = *reinterpret_cast<const float4*>(vals + e);
            {
                int b = r.x >> 7; int li = atomicAdd(&loff[b], 1);
                buk[lbase[b] + li] = make_uint2((unsigned)c.x | ((unsigned)(r.x & 127) << 20), __float_as_uint(v.x));
            }
            {
                int b = r.y >> 7; int li = atomicAdd(&loff[b], 1);
                buk[lbase[b] + li] = make_uint2((unsigned)c.y | ((unsigned)(r.y & 127) << 20), __float_as_uint(v.y));
            }
            {
                int b = r.z >> 7; int li = atomicAdd(&loff[b], 1);
                buk[lbase[b] + li] = make_uint2((unsigned)c.z | ((unsigned)(r.z & 127) << 20), __float_as_uint(v.z));
            }
            {
                int b = r.w >> 7; int li = atomicAdd(&loff[b], 1);
                buk[lbase[b] + li] = make_uint2((unsigned)c.w | ((unsigned)(r.w & 127) << 20), __float_as_uint(v.w));
            }
        } else {
            int lim = min(e + 4, e1);
            for (int k = e; k < lim; ++k) {
                int rr = rows[k];
                int b = rr >> 7; int li = atomicAdd(&loff[b], 1);
                buk[lbase[b] + li] = make_uint2((unsigned)cols[k] | ((unsigned)(rr & 127) << 20), __float_as_uint(vals[k]));
            }
        }
    }
}

__global__ __launch_bounds__(256) void bucket_to_csr_kernel(const uint2* __restrict__ buk,
                                                            const int* __restrict__ bbase,
                                                            const int* __restrict__ bend,
                                                            uint2* __restrict__ csr,
                                                            int* __restrict__ rp, int n) {
    __shared__ int lcnt[RPBUK];
    __shared__ int lofs[RPBUK];
    const int tid = threadIdx.x;
    const int b = blockIdx.x;
    const int start = bbase[b], end = bend[b];

    if (tid < RPBUK) lcnt[tid] = 0;
    __syncthreads();
    for (int j = start + tid; j < end; j += 256)
        atomicAdd(&lcnt[buk[j].x >> 20], 1);
    __syncthreads();
    if (tid < RPBUK) lofs[tid] = lcnt[tid];
    __syncthreads();
    for (int off = 1; off < RPBUK; off <<= 1) {
        int v = (tid < RPBUK && tid >= off) ? lofs[tid - off] : 0;
        __syncthreads();
        if (tid < RPBUK) lofs[tid] += v;   // inclusive scan
        __syncthreads();
    }
    if (tid < RPBUK) {
        int r = b * RPBUK + tid;
        if (r < n) rp[r] = start + lofs[tid];   // end offset of row r
        lofs[tid] -= lcnt[tid];                 // -> exclusive cursor
    }
    __syncthreads();
    for (int j = start + tid; j < end; j += 256) {
        uint2 e = buk[j];
        int rl = e.x >> 20;
        int pos = atomicAdd(&lofs[rl], 1);
        csr[start + pos] = make_uint2(e.x & 0xFFFFFu, e.y);
    }
}

// ---------------- FUSED K3+K4: SpMM -> LDS -> GEMM -> tanh ---------------
// Phase 1: proven bf16 gather (16 lanes/row, 8 bf16/lane), 4 sub-rounds of
// 16 rows into Ss (identical FP order to the standalone spmm).
// Phase 2: out rows = tanh(Ss @ M); M streamed from global (L1/L2-resident,
// shared by all blocks) so LDS stays 33 KB -> 4 blocks/CU.
__global__ __launch_bounds__(256, 4) void fused_spmm_gemm_kernel(
        const unsigned short* __restrict__ xb,
        const float* __restrict__ h0,
        const uint2* __restrict__ csr,
        const int* __restrict__ rp,
        const float* __restrict__ Mg,
        float* __restrict__ out, int n) {
    __shared__ float Ss[RPB][D + 1];   // 33 KB, stride 129: conflict-free reads
    const int tid = threadIdx.x;
    const int r0  = blockIdx.x * RPB;
    const int q   = tid & 15;          // elems 8q..8q+7
    const int rw  = tid >> 4;          // 0..15

#pragma unroll
    for (int sub = 0; sub < 4; ++sub) {
        const int sr = sub * 16 + rw;
        const int r  = r0 + sr;
        float acc[8] = {};
        if (r < n) {
            const int start = (r == 0) ? 0 : rp[r - 1];
            const int end   = rp[r];
            int j = start;
            for (; j + 1 < end; j += 2) {
                uint2 p0 = csr[j];
                uint2 p1 = csr[j + 1];
                float v0 = __uint_as_float(p0.y);
                float v1 = __uint_as_float(p1.y);
                uint4 a = *reinterpret_cast<const uint4*>(xb + (size_t)p0.x * D + q * 8);
                uint4 b = *reinterpret_cast<const uint4*>(xb + (size_t)p1.x * D + q * 8);
                const unsigned* aw = &a.x;
                const unsigned* bw = &b.x;
#pragma unroll
                for (int t = 0; t < 4; ++t) {
                    float alo = __uint_as_float(aw[t] << 16);
                    float ahi = __uint_as_float(aw[t] & 0xffff0000u);
                    acc[2 * t]     = fmaf(v0, alo, acc[2 * t]);
                    acc[2 * t + 1] = fmaf(v0, ahi, acc[2 * t + 1]);
                    float blo = __uint_as_float(bw[t] << 16);
                    float bhi = __uint_as_float(bw[t] & 0xffff0000u);
                    acc[2 * t]     = fmaf(v1, blo, acc[2 * t]);
                    acc[2 * t + 1] = fmaf(v1, bhi, acc[2 * t + 1]);
                }
            }
            if (j < end) {
                uint2 p0 = csr[j];
                float v0 = __uint_as_float(p0.y);
                uint4 a = *reinterpret_cast<const uint4*>(xb + (size_t)p0.x * D + q * 8);
                const unsigned* aw = &a.x;
#pragma unroll
                for (int t = 0; t < 4; ++t) {
                    float alo = __uint_as_float(aw[t] << 16);
                    float ahi = __uint_as_float(aw[t] & 0xffff0000u);
                    acc[2 * t]     = fmaf(v0, alo, acc[2 * t]);
                    acc[2 * t + 1] = fmaf(v0, ahi, acc[2 * t + 1]);
                }
            }
            const float4 hb0 = *reinterpret_cast<const float4*>(h0 + (size_t)r * D + q * 8);
            const float4 hb1 = *reinterpret_cast<const float4*>(h0 + (size_t)r * D + q * 8 + 4);
            acc[0] = 0.9f * acc[0] + 0.1f * hb0.x;
            acc[1] = 0.9f * acc[1] + 0.1f * hb0.y;
            acc[2] = 0.9f * acc[2] + 0.1f * hb0.z;
            acc[3] = 0.9f * acc[3] + 0.1f * hb0.w;
            acc[4] = 0.9f * acc[4] + 0.1f * hb1.x;
            acc[5] = 0.9f * acc[5] + 0.1f * hb1.y;
            acc[6] = 0.9f * acc[6] + 0.1f * hb1.z;
            acc[7] = 0.9f * acc[7] + 0.1f * hb1.w;
        }
#pragma unroll
        for (int i = 0; i < 8; ++i) Ss[sr][q * 8 + i] = acc[i];
    }
    __syncthreads();

    // Phase 2: 4x8 register tile per thread, M from global (L1/L2).
    const int tc = tid & 15;
    const int tr = tid >> 4;
    float acc2[4][8] = {};
#pragma unroll 8
    for (int k = 0; k < D; ++k) {
        float4 b0 = *reinterpret_cast<const float4*>(Mg + k * D + tc * 4);
        float4 b1 = *reinterpret_cast<const float4*>(Mg + k * D + 64 + tc * 4);
#pragma unroll
        for (int m = 0; m < 4; ++m) {
            float a = Ss[4 * tr + m][k];
            acc2[m][0] = fmaf(a, b0.x, acc2[m][0]);
            acc2[m][1] = fmaf(a, b0.y, acc2[m][1]);
            acc2[m][2] = fmaf(a, b0.z, acc2[m][2]);
            acc2[m][3] = fmaf(a, b0.w, acc2[m][3]);
            acc2[m][4] = fmaf(a, b1.x, acc2[m][4]);
            acc2[m][5] = fmaf(a, b1.y, acc2[m][5]);
            acc2[m][6] = fmaf(a, b1.z, acc2[m][6]);
            acc2[m][7] = fmaf(a, b1.w, acc2[m][7]);
        }
    }

#pragma unroll
    for (int m = 0; m < 4; ++m) {
        int r = r0 + 4 * tr + m;
        if (r >= n) continue;
        float4 o0, o1;
        o0.x = tanhf(acc2[m][0]); o0.y = tanhf(acc2[m][1]);
        o0.z = tanhf(acc2[m][2]); o0.w = tanhf(acc2[m][3]);
        o1.x = tanhf(acc2[m][4]); o1.y = tanhf(acc2[m][5]);
        o1.z = tanhf(acc2[m][6]); o1.w = tanhf(acc2[m][7]);
        *reinterpret_cast<float4*>(out + (size_t)r * D + tc * 4)      = o0;
        *reinterpret_cast<float4*>(out + (size_t)r * D + 64 + tc * 4) = o1;
    }
}

// -------- Fallback path kernels (minimal workspace) ----------------------
__global__ __launch_bounds__(256) void spmm_atomic_kernel(const float* __restrict__ x,
                                                          const float* __restrict__ vals,
                                                          const int* __restrict__ rows,
                                                          const int* __restrict__ cols,
                                                          float* __restrict__ hi, int E) {
    int tid = blockIdx.x * blockDim.x + threadIdx.x;
    int e = tid >> 5;
    if (e >= E) return;
    int q = tid & 31;
    float v = vals[e];
    int c = cols[e];
    int r = rows[e];
    const float4 xv = *reinterpret_cast<const float4*>(x + (size_t)c * D + q * 4);
    float* h = hi + (size_t)r * D + q * 4;
    unsafeAtomicAdd(h + 0, v * xv.x);
    unsafeAtomicAdd(h + 1, v * xv.y);
    unsafeAtomicAdd(h + 2, v * xv.z);
    unsafeAtomicAdd(h + 3, v * xv.w);
}

__global__ __launch_bounds__(256) void blend_kernel(const float* __restrict__ hi,
                                                    const float* __restrict__ h0,
                                                    float* __restrict__ S, int nd4) {
    int i = blockIdx.x * blockDim.x + threadIdx.x;
    if (i >= nd4) return;
    float4 a = reinterpret_cast<const float4*>(hi)[i];
    float4 b = reinterpret_cast<const float4*>(h0)[i];
    float4 s;
    s.x = 0.9f * a.x + 0.1f * b.x;
    s.y = 0.9f * a.y + 0.1f * b.y;
    s.z = 0.9f * a.z + 0.1f * b.z;
    s.w = 0.9f * a.w + 0.1f * b.w;
    reinterpret_cast<float4*>(S)[i] = s;
}

__global__ __launch_bounds__(256) void gemm_tanh_kernel(const float* __restrict__ S,
                                                        const float* __restrict__ Mg,
                                                        float* __restrict__ out, int n) {
    __shared__ float Ss[RPB][D + 1];
    const int tid = threadIdx.x;
    const int r0  = blockIdx.x * RPB;

    for (int i = tid; i < RPB * D / 4; i += 256) {
        int rr = (i * 4) / D, cc = (i * 4) & (D - 1);
        int r = r0 + rr;
        float4 a = (r < n) ? *reinterpret_cast<const float4*>(S + (size_t)r * D + cc)
                           : make_float4(0.f, 0.f, 0.f, 0.f);
        Ss[rr][cc + 0] = a.x;
        Ss[rr][cc + 1] = a.y;
        Ss[rr][cc + 2] = a.z;
        Ss[rr][cc + 3] = a.w;
    }
    __syncthreads();

    const int tc = tid & 15;
    const int tr = tid >> 4;
    float acc[4][8] = {};
#pragma unroll 8
    for (int k = 0; k < D; ++k) {
        float4 b0 = *reinterpret_cast<const float4*>(Mg + k * D + tc * 4);
        float4 b1 = *reinterpret_cast<const float4*>(Mg + k * D + 64 + tc * 4);
#pragma unroll
        for (int m = 0; m < 4; ++m) {
            float a = Ss[4 * tr + m][k];
            acc[m][0] = fmaf(a, b0.x, acc[m][0]);
            acc[m][1] = fmaf(a, b0.y, acc[m][1]);
            acc[m][2] = fmaf(a, b0.z, acc[m][2]);
            acc[m][3] = fmaf(a, b0.w, acc[m][3]);
            acc[m][4] = fmaf(a, b1.x, acc[m][4]);
            acc[m][5] = fmaf(a, b1.y, acc[m][5]);
            acc[m][6] = fmaf(a, b1.z, acc[m][6]);
            acc[m][7] = fmaf(a, b1.w, acc[m][7]);
        }
    }

#pragma unroll
    for (int m = 0; m < 4; ++m) {
        int r = r0 + 4 * tr + m;
        if (r >= n) continue;
        float4 o0, o1;
        o0.x = tanhf(acc[m][0]); o0.y = tanhf(acc[m][1]);
        o0.z = tanhf(acc[m][2]); o0.w = tanhf(acc[m][3]);
        o1.x = tanhf(acc[m][4]); o1.y = tanhf(acc[m][5]);
        o1.z = tanhf(acc[m][6]); o1.w = tanhf(acc[m][7]);
        *reinterpret_cast<float4*>(out + (size_t)r * D + tc * 4)      = o0;
        *reinterpret_cast<float4*>(out + (size_t)r * D + 64 + tc * 4) = o1;
    }
}

extern "C" void kernel_launch(void* const* d_in, const int* in_sizes, int n_in,
                              void* d_out, int out_size, void* d_ws, size_t ws_size,
                              hipStream_t stream) {
    const float* x  = (const float*)d_in[0];
    const float* h0 = (const float*)d_in[1];
    const float* W  = (const float*)d_in[2];
    const float* av = (const float*)d_in[3];
    const int*   ar = (const int*)d_in[4];
    const int*   ac = (const int*)d_in[5];
    const int*   lp = (const int*)d_in[6];
    float* out = (float*)d_out;

    const int nd = in_sizes[0];        // N*D
    const int n  = nd / D;             // N
    const int E  = in_sizes[3];
    const int nbuk  = (n + RPBUK - 1) / RPBUK;
    const int nblkE = (E + EPB - 1) / EPB;
    const int grid64 = (n + RPB - 1) / RPB;

    char* wsb = (char*)d_ws;
    float* A  = (float*)wsb;                                   // D*D
    float* Lg = A + D * D;                                     // D*D
    float* Mg = Lg + D * D;                                    // D*D
    size_t off = 3 * (size_t)D * D * sizeof(float);

    int* bcnt  = (int*)(wsb + off); off += NBUK_MAX * sizeof(int);
    int* bbase = (int*)(wsb + off); off += NBUK_MAX * sizeof(int);
    int* gcur  = (int*)(wsb + off); off += NBUK_MAX * sizeof(int);
    off = (off + 15) & ~(size_t)15;
    int* rp = (int*)(wsb + off); off += (size_t)n * sizeof(int);
    off = (off + 15) & ~(size_t)15;
    uint2* csr = (uint2*)(wsb + off); off += (size_t)E * sizeof(uint2);
    off = (off + 15) & ~(size_t)15;
    uint2* buk = (uint2*)(wsb + off); off += (size_t)E * sizeof(uint2);
    off = (off + 15) & ~(size_t)15;
    unsigned short* xb = (unsigned short*)(wsb + off);
    off += (size_t)nd * sizeof(unsigned short);
    off = (off + 15) & ~(size_t)15;
    const size_t need_core = off;

    if (ws_size >= need_core && nbuk <= NBUK_MAX && n < (1 << 20)) {
        hipMemsetAsync(bcnt, 0, NBUK_MAX * sizeof(int), stream);
        count_bucket_kernel<<<nblkE, 256, 0, stream>>>(ar, bcnt, E, nbuk);
        cvt_bf16_kernel<<<(nd / 8 + 255) / 256, 256, 0, stream>>>(x, xb, nd);
        wtw_kernel<<<D * D / 256, 256, 0, stream>>>(W, A);
        scan_bucket_kernel<<<1, 1024, 0, stream>>>(bcnt, bbase, gcur, nbuk);
        partition_kernel<<<nblkE, 256, 0, stream>>>(ar, ac, av, gcur, buk, E, nbuk);
        bucket_to_csr_kernel<<<nbuk, 256, 0, stream>>>(buk, bbase, gcur, csr, rp, n);
        chol_factor_kernel<<<1, 256, 0, stream>>>(A, Lg);
        solve_m_kernel<<<D, 64, 0, stream>>>(Lg, W, lp, Mg);
        fused_spmm_gemm_kernel<<<grid64, 256, 0, stream>>>(xb, h0, csr, rp, Mg, out, n);
    } else {
        float* hi = out;
        hipMemsetAsync(hi, 0, (size_t)nd * sizeof(float), stream);
        wtw_kernel<<<D * D / 256, 256, 0, stream>>>(W, A);
        spmm_atomic_kernel<<<(int)(((size_t)E * 32 + 255) / 256), 256, 0, stream>>>(x, av, ar, ac, hi, E);
        chol_factor_kernel<<<1, 256, 0, stream>>>(A, Lg);
        solve_m_kernel<<<D, 64, 0, stream>>>(Lg, W, lp, Mg);
        blend_kernel<<<(nd / 4 + 255) / 256, 256, 0, stream>>>(hi, h0, hi, nd / 4);
        gemm_tanh_kernel<<<grid64, 256, 0, stream>>>(hi, Mg, out, n);
    }
}